// Round 1
// baseline (2536.895 us; speedup 1.0000x reference)
//
#include <hip/hip_runtime.h>

#define N_USERS 100000
#define N_ITEMS 50000
#define N_NODES 150000
#define NNZ_EDGES 4000000
#define BATCH_SZ 16384
#define DIM 64
#define ALPHA 0.1f

// out[n][d] = ALPHA * x0[n][d], where x0 = concat(xu, xi). float4-vectorized.
__global__ void gtn_init_kernel(const float4* __restrict__ xu,
                                const float4* __restrict__ xi,
                                float4* __restrict__ out) {
    const int total4 = N_NODES * DIM / 4;
    const int boundary = N_USERS * DIM / 4;
    for (int i = blockIdx.x * blockDim.x + threadIdx.x; i < total4;
         i += gridDim.x * blockDim.x) {
        float4 v = (i < boundary) ? xu[i] : xi[i - boundary];
        out[i] = make_float4(ALPHA * v.x, ALPHA * v.y, ALPHA * v.z, ALPHA * v.w);
    }
}

// One wave (64 lanes) per edge; lane d handles dim d.
// out[row[e]][d] += (1-ALPHA) * w[e] * x[col[e]][d]
// x is given as two pointers (user part, item part) so layer 1 can read the
// original inputs without a concat copy; for ping-pong buffers pass
// (buf, buf + N_USERS*DIM).
__global__ void gtn_scatter_kernel(const float* __restrict__ xu,
                                   const float* __restrict__ xi,
                                   const float* __restrict__ w,
                                   const int* __restrict__ row,
                                   const int* __restrict__ col,
                                   float* __restrict__ out) {
    const int lane = threadIdx.x & 63;
    const long long wid = ((long long)blockIdx.x * blockDim.x + threadIdx.x) >> 6;
    const long long nwaves = ((long long)gridDim.x * blockDim.x) >> 6;
    for (long long e = wid; e < NNZ_EDGES; e += nwaves) {
        const int c = col[e];
        const int r = row[e];
        const float wv = (1.0f - ALPHA) * w[e];
        const float xval = (c < N_USERS) ? xu[c * DIM + lane]
                                         : xi[(c - N_USERS) * DIM + lane];
        atomicAdd(&out[r * DIM + lane], wv * xval);
    }
}

// One wave per batch element: gamma[b] = dot(x[users[b]], x[N_USERS+items[b]])
__global__ void gtn_dot_kernel(const float* __restrict__ x,
                               const int* __restrict__ users,
                               const int* __restrict__ items,
                               float* __restrict__ out) {
    const int lane = threadIdx.x & 63;
    const int wid = (blockIdx.x * blockDim.x + threadIdx.x) >> 6;
    if (wid >= BATCH_SZ) return;
    const int u = users[wid];
    const int it = items[wid];
    float p = x[(size_t)u * DIM + lane] *
              x[((size_t)N_USERS + it) * DIM + lane];
#pragma unroll
    for (int off = 32; off > 0; off >>= 1) p += __shfl_down(p, off, 64);
    if (lane == 0) out[wid] = p;
}

extern "C" void kernel_launch(void* const* d_in, const int* in_sizes, int n_in,
                              void* d_out, int out_size, void* d_ws, size_t ws_size,
                              hipStream_t stream) {
    const float* user_emb  = (const float*)d_in[0];
    const float* item_emb  = (const float*)d_in[1];
    const float* edge_vals = (const float*)d_in[2];
    const int*   row       = (const int*)d_in[3];
    const int*   col       = (const int*)d_in[4];
    const int*   users     = (const int*)d_in[5];
    const int*   items     = (const int*)d_in[6];
    float* out = (float*)d_out;

    float* bufA = (float*)d_ws;                         // 38.4 MB
    float* bufB = bufA + (size_t)N_NODES * DIM;         // 38.4 MB

    const dim3 blk(256);
    const dim3 initGrid(2048);
    const dim3 scatGrid(8192);      // 32768 waves, grid-stride over 4M edges
    const dim3 dotGrid((BATCH_SZ * 64) / 256);

    // Layer 1: bufA = ALPHA*x0 + (1-ALPHA)*S(x0)
    gtn_init_kernel<<<initGrid, blk, 0, stream>>>(
        (const float4*)user_emb, (const float4*)item_emb, (float4*)bufA);
    gtn_scatter_kernel<<<scatGrid, blk, 0, stream>>>(
        user_emb, item_emb, edge_vals, row, col, bufA);

    // Layer 2: bufB = ALPHA*x0 + (1-ALPHA)*S(bufA)
    gtn_init_kernel<<<initGrid, blk, 0, stream>>>(
        (const float4*)user_emb, (const float4*)item_emb, (float4*)bufB);
    gtn_scatter_kernel<<<scatGrid, blk, 0, stream>>>(
        bufA, bufA + (size_t)N_USERS * DIM, edge_vals, row, col, bufB);

    // Layer 3: bufA = ALPHA*x0 + (1-ALPHA)*S(bufB)
    gtn_init_kernel<<<initGrid, blk, 0, stream>>>(
        (const float4*)user_emb, (const float4*)item_emb, (float4*)bufA);
    gtn_scatter_kernel<<<scatGrid, blk, 0, stream>>>(
        bufB, bufB + (size_t)N_USERS * DIM, edge_vals, row, col, bufA);

    // gamma
    gtn_dot_kernel<<<dotGrid, blk, 0, stream>>>(bufA, users, items, out);
}

// Round 2
// 849.663 us; speedup vs baseline: 2.9858x; 2.9858x over previous
//
#include <hip/hip_runtime.h>

#define N_USERS 100000
#define N_ITEMS 50000
#define N_NODES 150000
#define NNZ_EDGES 4000000
#define BATCH_SZ 16384
#define DIM 64
#define ALPHA 0.1f
#define BETA 0.9f          // 1 - ALPHA
#define SCAN_B 1024
#define N_SCAN_BLOCKS ((N_NODES + SCAN_B - 1) / SCAN_B)   // 147

// ---------- CSR build ----------
__global__ void gtn_hist_kernel(const int* __restrict__ row, int* __restrict__ cnt) {
    const int stride = gridDim.x * blockDim.x;
    for (int e = blockIdx.x * blockDim.x + threadIdx.x; e < NNZ_EDGES; e += stride)
        atomicAdd(&cnt[row[e]], 1);
}

// block-local exclusive scan of cnt -> rowPtr, block sums -> bsum
__global__ void gtn_scan1_kernel(const int* __restrict__ cnt,
                                 int* __restrict__ rowPtr,
                                 int* __restrict__ bsum) {
    __shared__ int s[SCAN_B];
    const int i = blockIdx.x * SCAN_B + threadIdx.x;
    const int v = (i < N_NODES) ? cnt[i] : 0;
    s[threadIdx.x] = v;
    __syncthreads();
    for (int off = 1; off < SCAN_B; off <<= 1) {
        int t = (threadIdx.x >= off) ? s[threadIdx.x - off] : 0;
        __syncthreads();
        s[threadIdx.x] += t;
        __syncthreads();
    }
    if (i < N_NODES) rowPtr[i] = s[threadIdx.x] - v;   // exclusive within block
    if (threadIdx.x == SCAN_B - 1) bsum[blockIdx.x] = s[SCAN_B - 1];
}

// serial exclusive scan of 147 block sums (trivial)
__global__ void gtn_scan2_kernel(int* __restrict__ bsum) {
    int acc = 0;
    for (int i = 0; i < N_SCAN_BLOCKS; ++i) { int v = bsum[i]; bsum[i] = acc; acc += v; }
}

__global__ void gtn_scan3_kernel(int* __restrict__ rowPtr,
                                 const int* __restrict__ bsum,
                                 int* __restrict__ cursor) {
    const int i = blockIdx.x * SCAN_B + threadIdx.x;
    if (i < N_NODES) {
        const int p = rowPtr[i] + bsum[blockIdx.x];
        rowPtr[i] = p;
        cursor[i] = p;
    }
}

__global__ void gtn_fill_kernel(const int* __restrict__ row,
                                const int* __restrict__ col,
                                const float* __restrict__ w,
                                int* __restrict__ cursor,
                                int2* __restrict__ colw) {
    const int stride = gridDim.x * blockDim.x;
    for (int e = blockIdx.x * blockDim.x + threadIdx.x; e < NNZ_EDGES; e += stride) {
        const int r = row[e];
        const int pos = atomicAdd(&cursor[r], 1);
        colw[pos] = make_int2(col[e], __float_as_int(w[e]));
    }
}

// ---------- gather ----------
// Per-wave: agg[lane] = sum over edges of node: w * x[col][lane].
// Edge metadata loaded coalesced (one edge per lane) then broadcast by shuffle.
__device__ __forceinline__ float gtn_gather_row(int node, int lane,
        const float* __restrict__ xu, const float* __restrict__ xi,
        const int* __restrict__ rowPtr, const int* __restrict__ cnt,
        const int2* __restrict__ colw) {
    const int start = rowPtr[node];
    const int n = cnt[node];
    float acc0 = 0.f, acc1 = 0.f;
    for (int base = 0; base < n; base += 64) {
        const int m = min(64, n - base);
        int2 e = make_int2(0, 0);
        if (lane < m) e = colw[start + base + lane];
        int j = 0;
        for (; j + 1 < m; j += 2) {
            const int c0 = __shfl(e.x, j, 64);
            const float w0 = __int_as_float(__shfl(e.y, j, 64));
            const int c1 = __shfl(e.x, j + 1, 64);
            const float w1 = __int_as_float(__shfl(e.y, j + 1, 64));
            const float x0 = (c0 < N_USERS) ? xu[(size_t)c0 * DIM + lane]
                                            : xi[(size_t)(c0 - N_USERS) * DIM + lane];
            const float x1 = (c1 < N_USERS) ? xu[(size_t)c1 * DIM + lane]
                                            : xi[(size_t)(c1 - N_USERS) * DIM + lane];
            acc0 += w0 * x0;
            acc1 += w1 * x1;
        }
        if (j < m) {
            const int c0 = __shfl(e.x, j, 64);
            const float w0 = __int_as_float(__shfl(e.y, j, 64));
            const float x0 = (c0 < N_USERS) ? xu[(size_t)c0 * DIM + lane]
                                            : xi[(size_t)(c0 - N_USERS) * DIM + lane];
            acc0 += w0 * x0;
        }
    }
    return acc0 + acc1;
}

// out[node] = ALPHA * x0[node] + BETA * gather(node); one wave per node
__global__ void gtn_layer_kernel(const float* __restrict__ xu,
                                 const float* __restrict__ xi,
                                 const float* __restrict__ x0u,
                                 const float* __restrict__ x0i,
                                 const int* __restrict__ rowPtr,
                                 const int* __restrict__ cnt,
                                 const int2* __restrict__ colw,
                                 float* __restrict__ out) {
    const int lane = threadIdx.x & 63;
    const int node = (blockIdx.x * blockDim.x + threadIdx.x) >> 6;
    if (node >= N_NODES) return;
    const float agg = gtn_gather_row(node, lane, xu, xi, rowPtr, cnt, colw);
    const float x0v = (node < N_USERS) ? x0u[(size_t)node * DIM + lane]
                                       : x0i[(size_t)(node - N_USERS) * DIM + lane];
    out[(size_t)node * DIM + lane] = ALPHA * x0v + BETA * agg;
}

// Fused layer-3 + dot: only the 2*BATCH needed rows of x3 are ever computed.
__global__ void gtn_l3_dot_kernel(const float* __restrict__ xu,   // bufB user part
                                  const float* __restrict__ xi,   // bufB item part
                                  const float* __restrict__ x0u,
                                  const float* __restrict__ x0i,
                                  const int* __restrict__ rowPtr,
                                  const int* __restrict__ cnt,
                                  const int2* __restrict__ colw,
                                  const int* __restrict__ users,
                                  const int* __restrict__ items,
                                  float* __restrict__ out) {
    const int lane = threadIdx.x & 63;
    const int b = (blockIdx.x * blockDim.x + threadIdx.x) >> 6;
    if (b >= BATCH_SZ) return;
    const int u = users[b];
    const int it = items[b] + N_USERS;
    const float xu3 = ALPHA * x0u[(size_t)u * DIM + lane] +
                      BETA * gtn_gather_row(u, lane, xu, xi, rowPtr, cnt, colw);
    const float xi3 = ALPHA * x0i[(size_t)(it - N_USERS) * DIM + lane] +
                      BETA * gtn_gather_row(it, lane, xu, xi, rowPtr, cnt, colw);
    float p = xu3 * xi3;
#pragma unroll
    for (int off = 32; off > 0; off >>= 1) p += __shfl_down(p, off, 64);
    if (lane == 0) out[b] = p;
}

extern "C" void kernel_launch(void* const* d_in, const int* in_sizes, int n_in,
                              void* d_out, int out_size, void* d_ws, size_t ws_size,
                              hipStream_t stream) {
    const float* user_emb  = (const float*)d_in[0];
    const float* item_emb  = (const float*)d_in[1];
    const float* edge_vals = (const float*)d_in[2];
    const int*   row       = (const int*)d_in[3];
    const int*   col       = (const int*)d_in[4];
    const int*   users     = (const int*)d_in[5];
    const int*   items     = (const int*)d_in[6];
    float* out = (float*)d_out;

    // workspace layout
    char* p = (char*)d_ws;
    float* bufA   = (float*)p;  p += (size_t)N_NODES * DIM * sizeof(float);   // 38.4 MB
    float* bufB   = (float*)p;  p += (size_t)N_NODES * DIM * sizeof(float);   // 38.4 MB
    int2*  colw   = (int2*)p;   p += (size_t)NNZ_EDGES * sizeof(int2);        // 32 MB
    int*   cnt    = (int*)p;    p += (size_t)N_NODES * sizeof(int);
    int*   rowPtr = (int*)p;    p += (size_t)N_NODES * sizeof(int);
    int*   cursor = (int*)p;    p += (size_t)N_NODES * sizeof(int);
    int*   bsum   = (int*)p;    p += 256 * sizeof(int);

    const dim3 blk(256);

    // ---- CSR build ----
    hipMemsetAsync(cnt, 0, (size_t)N_NODES * sizeof(int), stream);
    gtn_hist_kernel<<<dim3(2048), blk, 0, stream>>>(row, cnt);
    gtn_scan1_kernel<<<dim3(N_SCAN_BLOCKS), dim3(SCAN_B), 0, stream>>>(cnt, rowPtr, bsum);
    gtn_scan2_kernel<<<dim3(1), dim3(1), 0, stream>>>(bsum);
    gtn_scan3_kernel<<<dim3(N_SCAN_BLOCKS), dim3(SCAN_B), 0, stream>>>(rowPtr, bsum, cursor);
    gtn_fill_kernel<<<dim3(2048), blk, 0, stream>>>(row, col, edge_vals, cursor, colw);

    // ---- layers (gather, one wave per node) ----
    const dim3 layerGrid((N_NODES * 64 + 255) / 256);   // 37500 blocks
    // L1: bufA = f(x0), x0 read directly from inputs
    gtn_layer_kernel<<<layerGrid, blk, 0, stream>>>(
        user_emb, item_emb, user_emb, item_emb, rowPtr, cnt, colw, bufA);
    // L2: bufB = f(bufA)
    gtn_layer_kernel<<<layerGrid, blk, 0, stream>>>(
        bufA, bufA + (size_t)N_USERS * DIM, user_emb, item_emb, rowPtr, cnt, colw, bufB);
    // L3 + dot fused, only at batch nodes
    const dim3 dotGrid((BATCH_SZ * 64) / 256);          // 4096 blocks
    gtn_l3_dot_kernel<<<dotGrid, blk, 0, stream>>>(
        bufB, bufB + (size_t)N_USERS * DIM, user_emb, item_emb,
        rowPtr, cnt, colw, users, items, out);
}

// Round 3
// 606.303 us; speedup vs baseline: 4.1842x; 1.4014x over previous
//
#include <hip/hip_runtime.h>

#define N_USERS 100000
#define N_ITEMS 50000
#define N_NODES 150000
#define NNZ_EDGES 4000000
#define BATCH_SZ 16384
#define DIM 64
#define ALPHA 0.1f
#define BETA 0.9f          // 1 - ALPHA
#define SCAN_B 1024
#define N_SCAN_BLOCKS ((N_NODES + SCAN_B - 1) / SCAN_B)   // 147

// ---------- CSR build ----------
// Pass A: histogram + per-edge rank (stored coalesced; atomic result feeds
// only a sequential store, not a scattered one).
__global__ void gtn_hist_rank_kernel(const int* __restrict__ row,
                                     int* __restrict__ cnt,
                                     int* __restrict__ rank) {
    const int e = blockIdx.x * blockDim.x + threadIdx.x;
    if (e < NNZ_EDGES) rank[e] = atomicAdd(&cnt[row[e]], 1);
}

// block-local exclusive scan of cnt -> rowPtr, block sums -> bsum
__global__ void gtn_scan1_kernel(const int* __restrict__ cnt,
                                 int* __restrict__ rowPtr,
                                 int* __restrict__ bsum) {
    __shared__ int s[SCAN_B];
    const int i = blockIdx.x * SCAN_B + threadIdx.x;
    const int v = (i < N_NODES) ? cnt[i] : 0;
    s[threadIdx.x] = v;
    __syncthreads();
    for (int off = 1; off < SCAN_B; off <<= 1) {
        int t = (threadIdx.x >= off) ? s[threadIdx.x - off] : 0;
        __syncthreads();
        s[threadIdx.x] += t;
        __syncthreads();
    }
    if (i < N_NODES) rowPtr[i] = s[threadIdx.x] - v;   // exclusive within block
    if (threadIdx.x == SCAN_B - 1) bsum[blockIdx.x] = s[SCAN_B - 1];
}

// serial exclusive scan of 147 block sums (trivial)
__global__ void gtn_scan2_kernel(int* __restrict__ bsum) {
    int acc = 0;
    for (int i = 0; i < N_SCAN_BLOCKS; ++i) { int v = bsum[i]; bsum[i] = acc; acc += v; }
}

__global__ void gtn_scan3_kernel(int* __restrict__ rowPtr,
                                 const int* __restrict__ bsum) {
    const int i = blockIdx.x * SCAN_B + threadIdx.x;
    if (i < N_NODES) rowPtr[i] += bsum[blockIdx.x];
}

// Pass B: atomic-free scatter. Every thread's store is independent -> full MLP.
__global__ void gtn_fill_kernel(const int* __restrict__ row,
                                const int* __restrict__ col,
                                const float* __restrict__ w,
                                const int* __restrict__ rank,
                                const int* __restrict__ rowPtr,
                                int2* __restrict__ colw) {
    const int e = blockIdx.x * blockDim.x + threadIdx.x;
    if (e >= NNZ_EDGES) return;
    const int pos = rowPtr[row[e]] + rank[e];
    colw[pos] = make_int2(col[e], __float_as_int(w[e]));
}

// ---------- gather ----------
// Per-wave: agg[lane] = sum over edges of node: w * x[col][lane].
// Edge metadata loaded coalesced (one edge per lane) then broadcast by shuffle.
__device__ __forceinline__ float gtn_gather_row(int node, int lane,
        const float* __restrict__ xu, const float* __restrict__ xi,
        const int* __restrict__ rowPtr, const int* __restrict__ cnt,
        const int2* __restrict__ colw) {
    const int start = rowPtr[node];
    const int n = cnt[node];
    float acc0 = 0.f, acc1 = 0.f;
    for (int base = 0; base < n; base += 64) {
        const int m = min(64, n - base);
        int2 e = make_int2(0, 0);
        if (lane < m) e = colw[start + base + lane];
        int j = 0;
        for (; j + 1 < m; j += 2) {
            const int c0 = __shfl(e.x, j, 64);
            const float w0 = __int_as_float(__shfl(e.y, j, 64));
            const int c1 = __shfl(e.x, j + 1, 64);
            const float w1 = __int_as_float(__shfl(e.y, j + 1, 64));
            const float x0 = (c0 < N_USERS) ? xu[(size_t)c0 * DIM + lane]
                                            : xi[(size_t)(c0 - N_USERS) * DIM + lane];
            const float x1 = (c1 < N_USERS) ? xu[(size_t)c1 * DIM + lane]
                                            : xi[(size_t)(c1 - N_USERS) * DIM + lane];
            acc0 += w0 * x0;
            acc1 += w1 * x1;
        }
        if (j < m) {
            const int c0 = __shfl(e.x, j, 64);
            const float w0 = __int_as_float(__shfl(e.y, j, 64));
            const float x0 = (c0 < N_USERS) ? xu[(size_t)c0 * DIM + lane]
                                            : xi[(size_t)(c0 - N_USERS) * DIM + lane];
            acc0 += w0 * x0;
        }
    }
    return acc0 + acc1;
}

// out[node] = ALPHA * x0[node] + BETA * gather(node); one wave per node
__global__ void gtn_layer_kernel(const float* __restrict__ xu,
                                 const float* __restrict__ xi,
                                 const float* __restrict__ x0u,
                                 const float* __restrict__ x0i,
                                 const int* __restrict__ rowPtr,
                                 const int* __restrict__ cnt,
                                 const int2* __restrict__ colw,
                                 float* __restrict__ out) {
    const int lane = threadIdx.x & 63;
    const int node = (blockIdx.x * blockDim.x + threadIdx.x) >> 6;
    if (node >= N_NODES) return;
    const float agg = gtn_gather_row(node, lane, xu, xi, rowPtr, cnt, colw);
    const float x0v = (node < N_USERS) ? x0u[(size_t)node * DIM + lane]
                                       : x0i[(size_t)(node - N_USERS) * DIM + lane];
    out[(size_t)node * DIM + lane] = ALPHA * x0v + BETA * agg;
}

// Fused layer-3 + dot: only the 2*BATCH needed rows of x3 are ever computed.
__global__ void gtn_l3_dot_kernel(const float* __restrict__ xu,   // bufB user part
                                  const float* __restrict__ xi,   // bufB item part
                                  const float* __restrict__ x0u,
                                  const float* __restrict__ x0i,
                                  const int* __restrict__ rowPtr,
                                  const int* __restrict__ cnt,
                                  const int2* __restrict__ colw,
                                  const int* __restrict__ users,
                                  const int* __restrict__ items,
                                  float* __restrict__ out) {
    const int lane = threadIdx.x & 63;
    const int b = (blockIdx.x * blockDim.x + threadIdx.x) >> 6;
    if (b >= BATCH_SZ) return;
    const int u = users[b];
    const int it = items[b] + N_USERS;
    const float xu3 = ALPHA * x0u[(size_t)u * DIM + lane] +
                      BETA * gtn_gather_row(u, lane, xu, xi, rowPtr, cnt, colw);
    const float xi3 = ALPHA * x0i[(size_t)(it - N_USERS) * DIM + lane] +
                      BETA * gtn_gather_row(it, lane, xu, xi, rowPtr, cnt, colw);
    float p = xu3 * xi3;
#pragma unroll
    for (int off = 32; off > 0; off >>= 1) p += __shfl_down(p, off, 64);
    if (lane == 0) out[b] = p;
}

extern "C" void kernel_launch(void* const* d_in, const int* in_sizes, int n_in,
                              void* d_out, int out_size, void* d_ws, size_t ws_size,
                              hipStream_t stream) {
    const float* user_emb  = (const float*)d_in[0];
    const float* item_emb  = (const float*)d_in[1];
    const float* edge_vals = (const float*)d_in[2];
    const int*   row       = (const int*)d_in[3];
    const int*   col       = (const int*)d_in[4];
    const int*   users     = (const int*)d_in[5];
    const int*   items     = (const int*)d_in[6];
    float* out = (float*)d_out;

    // workspace layout
    char* p = (char*)d_ws;
    float* bufA   = (float*)p;  p += (size_t)N_NODES * DIM * sizeof(float);   // 38.4 MB
    float* bufB   = (float*)p;  p += (size_t)N_NODES * DIM * sizeof(float);   // 38.4 MB
    int2*  colw   = (int2*)p;   p += (size_t)NNZ_EDGES * sizeof(int2);        // 32 MB
    int*   rank   = (int*)p;    p += (size_t)NNZ_EDGES * sizeof(int);         // 16 MB
    int*   cnt    = (int*)p;    p += (size_t)N_NODES * sizeof(int);
    int*   rowPtr = (int*)p;    p += (size_t)N_NODES * sizeof(int);
    int*   bsum   = (int*)p;    p += 256 * sizeof(int);

    const dim3 blk(256);
    const dim3 edgeGrid((NNZ_EDGES + 255) / 256);       // 15625 blocks, 1 edge/thread

    // ---- CSR build ----
    hipMemsetAsync(cnt, 0, (size_t)N_NODES * sizeof(int), stream);
    gtn_hist_rank_kernel<<<edgeGrid, blk, 0, stream>>>(row, cnt, rank);
    gtn_scan1_kernel<<<dim3(N_SCAN_BLOCKS), dim3(SCAN_B), 0, stream>>>(cnt, rowPtr, bsum);
    gtn_scan2_kernel<<<dim3(1), dim3(1), 0, stream>>>(bsum);
    gtn_scan3_kernel<<<dim3(N_SCAN_BLOCKS), dim3(SCAN_B), 0, stream>>>(rowPtr, bsum);
    gtn_fill_kernel<<<edgeGrid, blk, 0, stream>>>(row, col, edge_vals, rank, rowPtr, colw);

    // ---- layers (gather, one wave per node) ----
    const dim3 layerGrid((N_NODES * 64 + 255) / 256);   // 37500 blocks
    // L1: bufA = f(x0), x0 read directly from inputs
    gtn_layer_kernel<<<layerGrid, blk, 0, stream>>>(
        user_emb, item_emb, user_emb, item_emb, rowPtr, cnt, colw, bufA);
    // L2: bufB = f(bufA)
    gtn_layer_kernel<<<layerGrid, blk, 0, stream>>>(
        bufA, bufA + (size_t)N_USERS * DIM, user_emb, item_emb, rowPtr, cnt, colw, bufB);
    // L3 + dot fused, only at batch nodes
    const dim3 dotGrid((BATCH_SZ * 64) / 256);          // 4096 blocks
    gtn_l3_dot_kernel<<<dotGrid, blk, 0, stream>>>(
        bufB, bufB + (size_t)N_USERS * DIM, user_emb, item_emb,
        rowPtr, cnt, colw, users, items, out);
}

// Round 4
// 554.115 us; speedup vs baseline: 4.5783x; 1.0942x over previous
//
#include <hip/hip_runtime.h>

#define N_USERS 100000
#define N_ITEMS 50000
#define N_NODES 150000
#define NNZ_EDGES 4000000
#define BATCH_SZ 16384
#define DIM 64
#define ALPHA 0.1f
#define BETA 0.9f          // 1 - ALPHA
#define SCAN_B 1024
#define N_SCAN_BLOCKS ((N_NODES + SCAN_B - 1) / SCAN_B)   // 147

// ---------- CSR build ----------
// Pass A: histogram + per-edge rank (stored coalesced; atomic result feeds
// only a sequential store, not a scattered one).
__global__ void gtn_hist_rank_kernel(const int* __restrict__ row,
                                     int* __restrict__ cnt,
                                     int* __restrict__ rank) {
    const int e = blockIdx.x * blockDim.x + threadIdx.x;
    if (e < NNZ_EDGES) rank[e] = atomicAdd(&cnt[row[e]], 1);
}

// block-local exclusive scan of cnt -> rowPtr, block sums -> bsum
__global__ void gtn_scan1_kernel(const int* __restrict__ cnt,
                                 int* __restrict__ rowPtr,
                                 int* __restrict__ bsum) {
    __shared__ int s[SCAN_B];
    const int i = blockIdx.x * SCAN_B + threadIdx.x;
    const int v = (i < N_NODES) ? cnt[i] : 0;
    s[threadIdx.x] = v;
    __syncthreads();
    for (int off = 1; off < SCAN_B; off <<= 1) {
        int t = (threadIdx.x >= off) ? s[threadIdx.x - off] : 0;
        __syncthreads();
        s[threadIdx.x] += t;
        __syncthreads();
    }
    if (i < N_NODES) rowPtr[i] = s[threadIdx.x] - v;   // exclusive within block
    if (threadIdx.x == SCAN_B - 1) bsum[blockIdx.x] = s[SCAN_B - 1];
}

// serial exclusive scan of 147 block sums (trivial)
__global__ void gtn_scan2_kernel(int* __restrict__ bsum) {
    int acc = 0;
    for (int i = 0; i < N_SCAN_BLOCKS; ++i) { int v = bsum[i]; bsum[i] = acc; acc += v; }
}

__global__ void gtn_scan3_kernel(int* __restrict__ rowPtr,
                                 const int* __restrict__ bsum) {
    const int i = blockIdx.x * SCAN_B + threadIdx.x;
    if (i < N_NODES) rowPtr[i] += bsum[blockIdx.x];
}

// Pass B: atomic-free scatter. Every thread's store is independent -> full MLP.
__global__ void gtn_fill_kernel(const int* __restrict__ row,
                                const int* __restrict__ col,
                                const float* __restrict__ w,
                                const int* __restrict__ rank,
                                const int* __restrict__ rowPtr,
                                int2* __restrict__ colw) {
    const int e = blockIdx.x * blockDim.x + threadIdx.x;
    if (e >= NNZ_EDGES) return;
    const int pos = rowPtr[row[e]] + rank[e];
    colw[pos] = make_int2(col[e], __float_as_int(w[e]));
}

// ---------- gather (vectorized: 16 lanes x float4 per edge, 4 edges/wave) ----
// lane = grp*16 + sub. Group g handles edges 4j+g; each lane holds dims
// [4*sub, 4*sub+4) as a float4 partial accumulator. Invalid tail lanes carry
// (c=0, w=0) so the FMA is a harmless no-op against row 0 (branch-free).
__device__ __forceinline__ float4 gtn_gather_row_v4(
        int node, int lane, int sub, int grp,
        const float* __restrict__ xu, const float* __restrict__ xi,
        const int* __restrict__ rowPtr, const int* __restrict__ cnt,
        const int2* __restrict__ colw) {
    const int start = rowPtr[node];
    const int n = cnt[node];
    float4 acc = make_float4(0.f, 0.f, 0.f, 0.f);
    for (int base = 0; base < n; base += 64) {
        const int m = min(64, n - base);
        int2 e = make_int2(0, 0);
        if (lane < m) e = colw[start + base + lane];
        const int nj = (m + 3) >> 2;
        for (int j = 0; j < nj; ++j) {
            const int src = (j << 2) + grp;           // src <= 63 always
            const int c = __shfl(e.x, src, 64);
            const float wv = __int_as_float(__shfl(e.y, src, 64));
            const float4* xp = (c < N_USERS)
                ? (const float4*)(xu + (size_t)c * DIM)
                : (const float4*)(xi + (size_t)(c - N_USERS) * DIM);
            const float4 xv = xp[sub];
            acc.x = fmaf(wv, xv.x, acc.x);
            acc.y = fmaf(wv, xv.y, acc.y);
            acc.z = fmaf(wv, xv.z, acc.z);
            acc.w = fmaf(wv, xv.w, acc.w);
        }
    }
    return acc;
}

// butterfly-sum the 4 group partials; afterwards ALL lanes hold the full sum
__device__ __forceinline__ float4 gtn_reduce_groups(float4 a) {
    a.x += __shfl_xor(a.x, 16, 64);
    a.y += __shfl_xor(a.y, 16, 64);
    a.z += __shfl_xor(a.z, 16, 64);
    a.w += __shfl_xor(a.w, 16, 64);
    a.x += __shfl_xor(a.x, 32, 64);
    a.y += __shfl_xor(a.y, 32, 64);
    a.z += __shfl_xor(a.z, 32, 64);
    a.w += __shfl_xor(a.w, 32, 64);
    return a;
}

// out[node] = ALPHA * x0[node] + BETA * gather(node); one wave per node
__global__ void gtn_layer_kernel(const float* __restrict__ xu,
                                 const float* __restrict__ xi,
                                 const float* __restrict__ x0u,
                                 const float* __restrict__ x0i,
                                 const int* __restrict__ rowPtr,
                                 const int* __restrict__ cnt,
                                 const int2* __restrict__ colw,
                                 float* __restrict__ out) {
    const int lane = threadIdx.x & 63;
    const int sub = lane & 15;
    const int grp = lane >> 4;
    const int node = (blockIdx.x * blockDim.x + threadIdx.x) >> 6;
    if (node >= N_NODES) return;
    float4 agg = gtn_gather_row_v4(node, lane, sub, grp, xu, xi, rowPtr, cnt, colw);
    agg = gtn_reduce_groups(agg);
    if (grp == 0) {
        const float4 x0v = (node < N_USERS)
            ? ((const float4*)(x0u + (size_t)node * DIM))[sub]
            : ((const float4*)(x0i + (size_t)(node - N_USERS) * DIM))[sub];
        float4 o;
        o.x = ALPHA * x0v.x + BETA * agg.x;
        o.y = ALPHA * x0v.y + BETA * agg.y;
        o.z = ALPHA * x0v.z + BETA * agg.z;
        o.w = ALPHA * x0v.w + BETA * agg.w;
        ((float4*)(out + (size_t)node * DIM))[sub] = o;
    }
}

// Fused layer-3 + dot: only the 2*BATCH needed rows of x3 are ever computed.
__global__ void gtn_l3_dot_kernel(const float* __restrict__ xu,   // bufB user part
                                  const float* __restrict__ xi,   // bufB item part
                                  const float* __restrict__ x0u,
                                  const float* __restrict__ x0i,
                                  const int* __restrict__ rowPtr,
                                  const int* __restrict__ cnt,
                                  const int2* __restrict__ colw,
                                  const int* __restrict__ users,
                                  const int* __restrict__ items,
                                  float* __restrict__ out) {
    const int lane = threadIdx.x & 63;
    const int sub = lane & 15;
    const int grp = lane >> 4;
    const int b = (blockIdx.x * blockDim.x + threadIdx.x) >> 6;
    if (b >= BATCH_SZ) return;
    const int u = users[b];
    const int it = items[b] + N_USERS;

    float4 au = gtn_gather_row_v4(u, lane, sub, grp, xu, xi, rowPtr, cnt, colw);
    au = gtn_reduce_groups(au);
    float4 ai = gtn_gather_row_v4(it, lane, sub, grp, xu, xi, rowPtr, cnt, colw);
    ai = gtn_reduce_groups(ai);

    const float4 x0uv = ((const float4*)(x0u + (size_t)u * DIM))[sub];
    const float4 x0iv = ((const float4*)(x0i + (size_t)(it - N_USERS) * DIM))[sub];
    float4 vu, vi;
    vu.x = ALPHA * x0uv.x + BETA * au.x;  vi.x = ALPHA * x0iv.x + BETA * ai.x;
    vu.y = ALPHA * x0uv.y + BETA * au.y;  vi.y = ALPHA * x0iv.y + BETA * ai.y;
    vu.z = ALPHA * x0uv.z + BETA * au.z;  vi.z = ALPHA * x0iv.z + BETA * ai.z;
    vu.w = ALPHA * x0uv.w + BETA * au.w;  vi.w = ALPHA * x0iv.w + BETA * ai.w;

    float p = vu.x * vi.x + vu.y * vi.y + vu.z * vi.z + vu.w * vi.w;
    // reduce over the 16 subs (all 4 groups hold identical values)
    p += __shfl_xor(p, 1, 64);
    p += __shfl_xor(p, 2, 64);
    p += __shfl_xor(p, 4, 64);
    p += __shfl_xor(p, 8, 64);
    if (lane == 0) out[b] = p;
}

extern "C" void kernel_launch(void* const* d_in, const int* in_sizes, int n_in,
                              void* d_out, int out_size, void* d_ws, size_t ws_size,
                              hipStream_t stream) {
    const float* user_emb  = (const float*)d_in[0];
    const float* item_emb  = (const float*)d_in[1];
    const float* edge_vals = (const float*)d_in[2];
    const int*   row       = (const int*)d_in[3];
    const int*   col       = (const int*)d_in[4];
    const int*   users     = (const int*)d_in[5];
    const int*   items     = (const int*)d_in[6];
    float* out = (float*)d_out;

    // workspace layout
    char* p = (char*)d_ws;
    float* bufA   = (float*)p;  p += (size_t)N_NODES * DIM * sizeof(float);   // 38.4 MB
    float* bufB   = (float*)p;  p += (size_t)N_NODES * DIM * sizeof(float);   // 38.4 MB
    int2*  colw   = (int2*)p;   p += (size_t)NNZ_EDGES * sizeof(int2);        // 32 MB
    int*   rank   = (int*)p;    p += (size_t)NNZ_EDGES * sizeof(int);         // 16 MB
    int*   cnt    = (int*)p;    p += (size_t)N_NODES * sizeof(int);
    int*   rowPtr = (int*)p;    p += (size_t)N_NODES * sizeof(int);
    int*   bsum   = (int*)p;    p += 256 * sizeof(int);

    const dim3 blk(256);
    const dim3 edgeGrid((NNZ_EDGES + 255) / 256);       // 15625 blocks, 1 edge/thread

    // ---- CSR build ----
    hipMemsetAsync(cnt, 0, (size_t)N_NODES * sizeof(int), stream);
    gtn_hist_rank_kernel<<<edgeGrid, blk, 0, stream>>>(row, cnt, rank);
    gtn_scan1_kernel<<<dim3(N_SCAN_BLOCKS), dim3(SCAN_B), 0, stream>>>(cnt, rowPtr, bsum);
    gtn_scan2_kernel<<<dim3(1), dim3(1), 0, stream>>>(bsum);
    gtn_scan3_kernel<<<dim3(N_SCAN_BLOCKS), dim3(SCAN_B), 0, stream>>>(rowPtr, bsum);
    gtn_fill_kernel<<<edgeGrid, blk, 0, stream>>>(row, col, edge_vals, rank, rowPtr, colw);

    // ---- layers (gather, one wave per node) ----
    const dim3 layerGrid((N_NODES * 64 + 255) / 256);   // 37500 blocks
    // L1: bufA = f(x0), x0 read directly from inputs
    gtn_layer_kernel<<<layerGrid, blk, 0, stream>>>(
        user_emb, item_emb, user_emb, item_emb, rowPtr, cnt, colw, bufA);
    // L2: bufB = f(bufA)
    gtn_layer_kernel<<<layerGrid, blk, 0, stream>>>(
        bufA, bufA + (size_t)N_USERS * DIM, user_emb, item_emb, rowPtr, cnt, colw, bufB);
    // L3 + dot fused, only at batch nodes
    const dim3 dotGrid((BATCH_SZ * 64) / 256);          // 4096 blocks
    gtn_l3_dot_kernel<<<dotGrid, blk, 0, stream>>>(
        bufB, bufB + (size_t)N_USERS * DIM, user_emb, item_emb,
        rowPtr, cnt, colw, users, items, out);
}